// Round 1
// baseline (7135.042 us; speedup 1.0000x reference)
//
#include <hip/hip_runtime.h>
#include <hip/hip_bf16.h>

typedef __attribute__((ext_vector_type(8))) short short8;
typedef __attribute__((ext_vector_type(4))) float f32x4;

#define SQLEN 256
#define BATCH 128
#define HID   1024
#define G4    4096
#define NCLS  1000

static __device__ __forceinline__ float sigm(float x){ return 1.0f/(1.0f+__expf(-x)); }
static __device__ __forceinline__ float tanhx(float x){ return 2.0f/(1.0f+__expf(-2.0f*x)) - 1.0f; }
static __device__ __forceinline__ short bf16b(float x){
  __hip_bfloat16 h = __float2bfloat16(x);
  return __builtin_bit_cast(short, h);
}
static __device__ __forceinline__ float bf2f(short s){
  return __bfloat162float(__builtin_bit_cast(__hip_bfloat16, s));
}

// ---- prep: cast x [B][S][I] fp32 -> xbf [(s*128+b)][I] bf16 (permuted) ----
__global__ void cast_x_kernel(const float* __restrict__ x, short* __restrict__ xbf){
  int r = blockIdx.x;            // r = s*128 + b
  int s = r >> 7, b = r & 127;
  const float* src = x + ((size_t)b*SQLEN + s)*HID;
  short* dst = xbf + (size_t)r*HID;
  int k = threadIdx.x*4;
  float4 v = *(const float4*)(src + k);
  short4 o; o.x=bf16b(v.x); o.y=bf16b(v.y); o.z=bf16b(v.z); o.w=bf16b(v.w);
  *(short4*)(dst + k) = o;
}

// ---- prep: generic fp32 -> bf16 cast (n divisible by 1024) ----
__global__ void cast_w_kernel(const float* __restrict__ src, short* __restrict__ dst){
  int i = (blockIdx.x*256 + threadIdx.x)*4;
  float4 v = *(const float4*)(src + i);
  short4 o; o.x=bf16b(v.x); o.y=bf16b(v.y); o.z=bf16b(v.z); o.w=bf16b(v.w);
  *(short4*)(dst + i) = o;
}

__global__ void bias_kernel(const float* __restrict__ a, const float* __restrict__ b,
                            float* __restrict__ o){
  int i = blockIdx.x*256 + threadIdx.x;
  o[i] = a[i] + b[i];
}

// ---- phase 1: xw[r][n] = sum_k xbf[r][k]*Wxh[n][k] + bias[n], bf16 out ----
// M=32768, N=4096, K=1024. 128x128 tile, BK=32, 256 thr (4 waves, 2x2 of 64x64).
__global__ __launch_bounds__(256,2) void gemm_xw_kernel(
    const short* __restrict__ A, const short* __restrict__ B,
    const float* __restrict__ bias, short* __restrict__ C)
{
  __shared__ __align__(16) short As[4096];   // [128][32]
  __shared__ __align__(16) short Bs[4096];
  const int tid = threadIdx.x;
  const int bm = blockIdx.x >> 5;     // 0..255
  const int bn = blockIdx.x & 31;     // 0..31
  const size_t r0 = (size_t)bm*128, n0 = (size_t)bn*128;
  const int lane = tid & 63, wave = tid >> 6;
  const int wm = (wave>>1)*64, wn = (wave&1)*64;
  const int l15 = lane & 15, quad = lane >> 4;

  f32x4 acc[4][4];
  #pragma unroll
  for (int m=0;m<4;++m)
    #pragma unroll
    for (int n=0;n<4;++n) acc[m][n] = (f32x4)0.0f;

  for (int kk = 0; kk < 32; ++kk){
    const int k0 = kk*32;
    short8 av[2], bv[2];
    #pragma unroll
    for (int rep=0; rep<2; ++rep){
      int c = rep*256 + tid;
      int row = c >> 2, ko = (c & 3)*8;
      av[rep] = *(const short8*)(A + (r0+row)*HID + k0 + ko);
      bv[rep] = *(const short8*)(B + (n0+row)*HID + k0 + ko);
    }
    __syncthreads();   // previous iter's LDS reads done
    #pragma unroll
    for (int rep=0; rep<2; ++rep){
      int c = rep*256 + tid;
      *(short8*)(As + c*8) = av[rep];
      *(short8*)(Bs + c*8) = bv[rep];
    }
    __syncthreads();   // tiles ready
    short8 af[4], bf[4];
    #pragma unroll
    for (int m=0;m<4;++m) af[m] = *(const short8*)(As + (wm + m*16 + l15)*32 + quad*8);
    #pragma unroll
    for (int n=0;n<4;++n) bf[n] = *(const short8*)(Bs + (wn + n*16 + l15)*32 + quad*8);
    #pragma unroll
    for (int m=0;m<4;++m)
      #pragma unroll
      for (int n=0;n<4;++n)
        acc[m][n] = __builtin_amdgcn_mfma_f32_16x16x32_bf16(af[m], bf[n], acc[m][n], 0,0,0);
  }
  __syncthreads();
  #pragma unroll
  for (int n=0;n<4;++n){
    float bs = bias[n0 + wn + n*16 + l15];
    size_t nn = n0 + wn + n*16 + l15;
    #pragma unroll
    for (int m=0;m<4;++m){
      #pragma unroll
      for (int rg=0; rg<4; ++rg){
        size_t r = r0 + wm + m*16 + quad*4 + rg;
        C[r*G4 + nn] = bf16b(acc[m][n][rg] + bs);
      }
    }
  }
}

// ---- phase 2: persistent LSTM recurrence ----
// 256 blocks = 4 b-groups (32 rows) x 64 j-groups (16 hidden units).
// Whh frags live in registers for all 256 steps; K split 4x256 across waves;
// cross-wave reduce via LDS; c-state in LDS; per-b-group 64-block flag barrier.
__global__ __launch_bounds__(256,1) void lstm_kernel(
    const short* __restrict__ whh, const short* __restrict__ xw,
    short* __restrict__ h0, short* __restrict__ h1, unsigned* __restrict__ cnt)
{
  const int tid  = threadIdx.x;
  const int lane = tid & 63;
  const int wave = tid >> 6;         // K-slice 0..3
  const int l15  = lane & 15;
  const int quad = lane >> 4;
  const int bg = blockIdx.x >> 6;    // 0..3
  const int jg = blockIdx.x & 63;    // 0..63
  const int b0 = bg*32;
  const int j0 = jg*16;
  const int ks0 = wave*256;

  // Whh fragments -> registers (once). B-frag: n = lane&15, k = quad*8+j
  short8 Bf[4][8];
  #pragma unroll
  for (int g=0; g<4; ++g){
    const short* src = whh + (size_t)(g*1024 + j0 + l15)*HID + ks0 + quad*8;
    #pragma unroll
    for (int kit=0; kit<8; ++kit)
      Bf[g][kit] = *(const short8*)(src + kit*32);
  }

  __shared__ f32x4 part[4][8][64];   // [wave][mt*4+g][lane]  32KB
  __shared__ float c_lds[32][16];    // cell state, fp32
  { int o1 = tid, o2 = tid + 256;
    c_lds[o1>>4][o1&15] = 0.0f;
    c_lds[o2>>4][o2&15] = 0.0f; }

  unsigned* mycnt = cnt + bg*64;     // 256B-spaced counters

  for (int t = 0; t < SQLEN; ++t){
    const short* hin  = (t & 1) ? h1 : h0;
    short*       hout = (t & 1) ? h0 : h1;

    // prefetch all A (h) fragments for this step's K-slice
    short8 Af[2][8];
    #pragma unroll
    for (int kit=0; kit<8; ++kit){
      Af[0][kit] = *(const short8*)(hin + (size_t)(b0      + l15)*HID + ks0 + kit*32 + quad*8);
      Af[1][kit] = *(const short8*)(hin + (size_t)(b0 + 16 + l15)*HID + ks0 + kit*32 + quad*8);
    }
    f32x4 acc[2][4];
    #pragma unroll
    for (int mt=0; mt<2; ++mt)
      #pragma unroll
      for (int g=0; g<4; ++g) acc[mt][g] = (f32x4)0.0f;
    #pragma unroll
    for (int kit=0; kit<8; ++kit){
      #pragma unroll
      for (int g=0; g<4; ++g){
        acc[0][g] = __builtin_amdgcn_mfma_f32_16x16x32_bf16(Af[0][kit], Bf[g][kit], acc[0][g],0,0,0);
        acc[1][g] = __builtin_amdgcn_mfma_f32_16x16x32_bf16(Af[1][kit], Bf[g][kit], acc[1][g],0,0,0);
      }
    }
    #pragma unroll
    for (int mt=0; mt<2; ++mt)
      #pragma unroll
      for (int g=0; g<4; ++g)
        part[wave][mt*4+g][lane] = acc[mt][g];
    __syncthreads();

    // elementwise: 512 (b,j) cells, 2 per thread
    #pragma unroll
    for (int i=0; i<2; ++i){
      int o  = tid + i*256;
      int bl = o >> 4, jj = o & 15;
      int mt = bl >> 4, r = bl & 15;
      int ln = (r>>2)*16 + jj, rg = r & 3;
      float gs[4];
      #pragma unroll
      for (int g=0; g<4; ++g){
        int f = mt*4 + g;
        const float* p0 = (const float*)&part[0][f][ln];
        const float* p1 = (const float*)&part[1][f][ln];
        const float* p2 = (const float*)&part[2][f][ln];
        const float* p3 = (const float*)&part[3][f][ln];
        float xwv = bf2f(xw[((size_t)t*BATCH + b0 + bl)*G4 + g*1024 + j0 + jj]);
        gs[g] = p0[rg] + p1[rg] + p2[rg] + p3[rg] + xwv;
      }
      float it = sigm(gs[0]);
      float ft = sigm(gs[1]);
      float ch = tanhx(gs[2]);
      float ot = sigm(gs[3]);
      float cv = c_lds[bl][jj];
      float cn = cv*ft + it*ch;
      c_lds[bl][jj] = cn;
      hout[(size_t)(b0 + bl)*HID + j0 + jj] = bf16b(ot * tanhx(cn));
    }
    __syncthreads();   // all h stores drained (vmcnt0 at barrier), part[] reusable

    if (t < SQLEN-1){
      if (tid == 0){
        __threadfence();  // agent release: flush this XCD's writes
        __hip_atomic_fetch_add(mycnt, 1u, __ATOMIC_RELEASE, __HIP_MEMORY_SCOPE_AGENT);
        unsigned target = 64u*(unsigned)(t+1);
        while (__hip_atomic_load(mycnt, __ATOMIC_ACQUIRE, __HIP_MEMORY_SCOPE_AGENT) < target)
          __builtin_amdgcn_s_sleep(2);
        __threadfence();  // agent acquire: invalidate L1/L2 before reading new h
      }
      __syncthreads();
    }
  }
}

// ---- phase 3: out[b][c] = h[b]. Wfc[c] + bfc[c], fp32 ----
__global__ __launch_bounds__(256) void fc_kernel(const short* __restrict__ h,
    const float* __restrict__ wfc, const float* __restrict__ bfc, float* __restrict__ out)
{
  __shared__ float hs[4][1024];
  int tid = threadIdx.x;
  int b0 = blockIdx.x*4;
  for (int i = tid; i < 4096; i += 256){
    int bb = i >> 10, k = i & 1023;
    hs[bb][k] = bf2f(h[(size_t)(b0+bb)*HID + k]);
  }
  __syncthreads();
  for (int c = tid; c < NCLS; c += 256){
    const float* w = wfc + (size_t)c*HID;
    float a0=0.f,a1=0.f,a2=0.f,a3=0.f;
    for (int k=0; k<1024; k+=4){
      float4 wv = *(const float4*)(w + k);
      a0 += wv.x*hs[0][k] + wv.y*hs[0][k+1] + wv.z*hs[0][k+2] + wv.w*hs[0][k+3];
      a1 += wv.x*hs[1][k] + wv.y*hs[1][k+1] + wv.z*hs[1][k+2] + wv.w*hs[1][k+3];
      a2 += wv.x*hs[2][k] + wv.y*hs[2][k+1] + wv.z*hs[2][k+2] + wv.w*hs[2][k+3];
      a3 += wv.x*hs[3][k] + wv.y*hs[3][k+1] + wv.z*hs[3][k+2] + wv.w*hs[3][k+3];
    }
    float bb = bfc[c];
    out[(size_t)(b0+0)*NCLS + c] = a0 + bb;
    out[(size_t)(b0+1)*NCLS + c] = a1 + bb;
    out[(size_t)(b0+2)*NCLS + c] = a2 + bb;
    out[(size_t)(b0+3)*NCLS + c] = a3 + bb;
  }
}

extern "C" void kernel_launch(void* const* d_in, const int* in_sizes, int n_in,
                              void* d_out, int out_size, void* d_ws, size_t ws_size,
                              hipStream_t stream) {
  const float* x   = (const float*)d_in[0];
  const float* Wxh = (const float*)d_in[1];
  const float* bxh = (const float*)d_in[2];
  const float* Whh = (const float*)d_in[3];
  const float* bhh = (const float*)d_in[4];
  const float* Wfc = (const float*)d_in[5];
  const float* bfc = (const float*)d_in[6];
  float* out = (float*)d_out;

  char* ws = (char*)d_ws;
  // workspace layout (bytes)
  short*    xbf   = (short*)(ws + 0);            // 32768*1024*2  = 64MB
  short*    wxhb  = (short*)(ws + 67108864);     // 8MB
  short*    whhb  = (short*)(ws + 75497472);     // 8MB
  float*    biasg = (float*)(ws + 83886080);     // 16KB
  short*    xw    = (short*)(ws + 83951616);     // 32768*4096*2 = 256MB
  short*    h0    = (short*)(ws + 352387072);    // 256KB
  short*    h1    = (short*)(ws + 352649216);    // 256KB
  unsigned* cnt   = (unsigned*)(ws + 352911360); // 4 counters, 256B apart

  // zero h buffers + counters
  hipMemsetAsync(ws + 352387072, 0, 2*262144 + 4096, stream);

  cast_x_kernel<<<32768, 256, 0, stream>>>(x, xbf);
  cast_w_kernel<<<4096, 256, 0, stream>>>(Wxh, wxhb);
  cast_w_kernel<<<4096, 256, 0, stream>>>(Whh, whhb);
  bias_kernel  <<<16,   256, 0, stream>>>(bxh, bhh, biasg);
  gemm_xw_kernel<<<8192, 256, 0, stream>>>(xbf, wxhb, biasg, xw);
  lstm_kernel  <<<256,  256, 0, stream>>>(whhb, xw, h0, h1, cnt);
  fc_kernel    <<<32,   256, 0, stream>>>(h0, Wfc, bfc, out);
}

// Round 2
// 3145.392 us; speedup vs baseline: 2.2684x; 2.2684x over previous
//
#include <hip/hip_runtime.h>
#include <hip/hip_bf16.h>

typedef __attribute__((ext_vector_type(8))) short short8;
typedef __attribute__((ext_vector_type(4))) float f32x4;
typedef __attribute__((ext_vector_type(2))) unsigned long long u64x2;
typedef unsigned long long u64;
typedef unsigned int u32;

#define SQLEN 256
#define BATCH 128
#define HID   1024
#define G4    4096
#define NCLS  1000

static __device__ __forceinline__ float sigm(float x){ return 1.0f/(1.0f+__expf(-x)); }
static __device__ __forceinline__ float tanhx(float x){ return 2.0f/(1.0f+__expf(-2.0f*x)) - 1.0f; }
static __device__ __forceinline__ short bf16b(float x){
  __hip_bfloat16 h = __float2bfloat16(x);
  return __builtin_bit_cast(short, h);
}
static __device__ __forceinline__ float bf2f(short s){
  return __bfloat162float(__builtin_bit_cast(__hip_bfloat16, s));
}

// ---- prep: cast x [B][S][I] fp32 -> xbf [(s*128+b)][I] bf16 (permuted) ----
__global__ void cast_x_kernel(const float* __restrict__ x, short* __restrict__ xbf){
  int r = blockIdx.x;            // r = s*128 + b
  int s = r >> 7, b = r & 127;
  const float* src = x + ((size_t)b*SQLEN + s)*HID;
  short* dst = xbf + (size_t)r*HID;
  int k = threadIdx.x*4;
  float4 v = *(const float4*)(src + k);
  short4 o; o.x=bf16b(v.x); o.y=bf16b(v.y); o.z=bf16b(v.z); o.w=bf16b(v.w);
  *(short4*)(dst + k) = o;
}

// ---- prep: generic fp32 -> bf16 cast (n divisible by 1024) ----
__global__ void cast_w_kernel(const float* __restrict__ src, short* __restrict__ dst){
  int i = (blockIdx.x*256 + threadIdx.x)*4;
  float4 v = *(const float4*)(src + i);
  short4 o; o.x=bf16b(v.x); o.y=bf16b(v.y); o.z=bf16b(v.z); o.w=bf16b(v.w);
  *(short4*)(dst + i) = o;
}

__global__ void bias_kernel(const float* __restrict__ a, const float* __restrict__ b,
                            float* __restrict__ o){
  int i = blockIdx.x*256 + threadIdx.x;
  o[i] = a[i] + b[i];
}

// ---- phase 1: xw[r][n] = sum_k xbf[r][k]*Wxh[n][k] + bias[n], bf16 out ----
__global__ __launch_bounds__(256,2) void gemm_xw_kernel(
    const short* __restrict__ A, const short* __restrict__ B,
    const float* __restrict__ bias, short* __restrict__ C)
{
  __shared__ __align__(16) short As[4096];   // [128][32]
  __shared__ __align__(16) short Bs[4096];
  const int tid = threadIdx.x;
  const int bm = blockIdx.x >> 5;     // 0..255
  const int bn = blockIdx.x & 31;     // 0..31
  const size_t r0 = (size_t)bm*128, n0 = (size_t)bn*128;
  const int lane = tid & 63, wave = tid >> 6;
  const int wm = (wave>>1)*64, wn = (wave&1)*64;
  const int l15 = lane & 15, quad = lane >> 4;

  f32x4 acc[4][4];
  #pragma unroll
  for (int m=0;m<4;++m)
    #pragma unroll
    for (int n=0;n<4;++n) acc[m][n] = (f32x4)0.0f;

  for (int kk = 0; kk < 32; ++kk){
    const int k0 = kk*32;
    short8 av[2], bv[2];
    #pragma unroll
    for (int rep=0; rep<2; ++rep){
      int c = rep*256 + tid;
      int row = c >> 2, ko = (c & 3)*8;
      av[rep] = *(const short8*)(A + (r0+row)*HID + k0 + ko);
      bv[rep] = *(const short8*)(B + (n0+row)*HID + k0 + ko);
    }
    __syncthreads();
    #pragma unroll
    for (int rep=0; rep<2; ++rep){
      int c = rep*256 + tid;
      *(short8*)(As + c*8) = av[rep];
      *(short8*)(Bs + c*8) = bv[rep];
    }
    __syncthreads();
    short8 af[4], bf[4];
    #pragma unroll
    for (int m=0;m<4;++m) af[m] = *(const short8*)(As + (wm + m*16 + l15)*32 + quad*8);
    #pragma unroll
    for (int n=0;n<4;++n) bf[n] = *(const short8*)(Bs + (wn + n*16 + l15)*32 + quad*8);
    #pragma unroll
    for (int m=0;m<4;++m)
      #pragma unroll
      for (int n=0;n<4;++n)
        acc[m][n] = __builtin_amdgcn_mfma_f32_16x16x32_bf16(af[m], bf[n], acc[m][n], 0,0,0);
  }
  __syncthreads();
  #pragma unroll
  for (int n=0;n<4;++n){
    float bs = bias[n0 + wn + n*16 + l15];
    size_t nn = n0 + wn + n*16 + l15;
    #pragma unroll
    for (int m=0;m<4;++m){
      #pragma unroll
      for (int rg=0; rg<4; ++rg){
        size_t r = r0 + wm + m*16 + quad*4 + rg;
        C[r*G4 + nn] = bf16b(acc[m][n][rg] + bs);
      }
    }
  }
}

// ---- phase 2: persistent LSTM recurrence ----
// 256 blocks = 4 b-groups (32 batch rows) x 64 j-groups (16 hidden units).
// Whh frags in registers for all 256 steps. h exchanged via relaxed agent-scope
// (sc1) atomics -> no fences, no L2 invalidates, ever. Per-block flag words;
// wave 0 polls all 64 flags lane-parallel with relaxed loads.
__global__ __launch_bounds__(256,1) void lstm_kernel(
    const short* __restrict__ whh, const short* __restrict__ xw,
    short* __restrict__ h0, short* __restrict__ h1, u32* __restrict__ flags)
{
  const int tid  = threadIdx.x;
  const int lane = tid & 63;
  const int wave = tid >> 6;         // K-slice 0..3
  const int l15  = lane & 15;
  const int quad = lane >> 4;
  const int bg = blockIdx.x >> 6;    // 0..3
  const int jg = blockIdx.x & 63;    // 0..63
  const int b0 = bg*32;
  const int j0 = jg*16;
  const int ks0 = wave*256;

  // Whh fragments -> registers (once). B-frag: n = lane&15, k = quad*8+j
  short8 Bf[4][8];
  #pragma unroll
  for (int g=0; g<4; ++g){
    const short* src = whh + (size_t)(g*1024 + j0 + l15)*HID + ks0 + quad*8;
    #pragma unroll
    for (int kit=0; kit<8; ++kit)
      Bf[g][kit] = *(const short8*)(src + kit*32);
  }

  __shared__ f32x4 part[4][8][64];   // [wave][mt*4+g][lane]  32KB
  __shared__ float c_lds[32][16];    // cell state, fp32
  { int o1 = tid, o2 = tid + 256;
    c_lds[o1>>4][o1&15] = 0.0f;
    c_lds[o2>>4][o2&15] = 0.0f; }

  u32* myflags = flags + bg*64;
  const int ebl = tid >> 3;          // elementwise cell pair: batch row 0..31
  const int ejj = (tid & 7)*2;       // even hidden col within block's 16

  for (int t = 0; t < SQLEN; ++t){
    const short* hin  = (t & 1) ? h1 : h0;
    short*       hout = (t & 1) ? h0 : h1;

    // prefetch xw gate pairs for this thread's elementwise cells
    u32 xwp[4];
    {
      const u32* base = (const u32*)(xw + ((size_t)t*BATCH + b0 + ebl)*G4 + j0 + ejj);
      #pragma unroll
      for (int g=0; g<4; ++g) xwp[g] = base[g*512];
    }

    // load A (h) fragments for this step's K-slice: relaxed agent (sc1) loads
    short8 Af[2][8];
    #pragma unroll
    for (int kit=0; kit<8; ++kit){
      #pragma unroll
      for (int mt=0; mt<2; ++mt){
        const u64* p = (const u64*)(hin + (size_t)(b0 + mt*16 + l15)*HID + ks0 + kit*32 + quad*8);
        u64x2 v;
        v.x = __hip_atomic_load(p,   __ATOMIC_RELAXED, __HIP_MEMORY_SCOPE_AGENT);
        v.y = __hip_atomic_load(p+1, __ATOMIC_RELAXED, __HIP_MEMORY_SCOPE_AGENT);
        Af[mt][kit] = __builtin_bit_cast(short8, v);
      }
    }

    f32x4 acc[2][4];
    #pragma unroll
    for (int mt=0; mt<2; ++mt)
      #pragma unroll
      for (int g=0; g<4; ++g) acc[mt][g] = (f32x4)0.0f;
    #pragma unroll
    for (int kit=0; kit<8; ++kit){
      #pragma unroll
      for (int g=0; g<4; ++g){
        acc[0][g] = __builtin_amdgcn_mfma_f32_16x16x32_bf16(Af[0][kit], Bf[g][kit], acc[0][g],0,0,0);
        acc[1][g] = __builtin_amdgcn_mfma_f32_16x16x32_bf16(Af[1][kit], Bf[g][kit], acc[1][g],0,0,0);
      }
    }
    #pragma unroll
    for (int mt=0; mt<2; ++mt)
      #pragma unroll
      for (int g=0; g<4; ++g)
        part[wave][mt*4+g][lane] = acc[mt][g];
    __syncthreads();

    // elementwise: 512 cells as 256 adjacent-jj pairs, one per thread
    {
      const int bl = ebl, jj = ejj;
      const int mt = bl >> 4, r = bl & 15;
      const int ln = (r>>2)*16 + jj, rg = r & 3;
      float gs0[4], gs1[4];
      #pragma unroll
      for (int g=0; g<4; ++g){
        const int f = mt*4 + g;
        float s0 = 0.f, s1 = 0.f;
        #pragma unroll
        for (int w=0; w<4; ++w){
          const float* p = (const float*)&part[w][f][ln];
          s0 += p[rg]; s1 += p[4+rg];   // [ln] and [ln+1] are adjacent f32x4
        }
        gs0[g] = s0 + bf2f((short)(xwp[g] & 0xffff));
        gs1[g] = s1 + bf2f((short)(xwp[g] >> 16));
      }
      float it0 = sigm(gs0[0]), ft0 = sigm(gs0[1]), ch0 = tanhx(gs0[2]), ot0 = sigm(gs0[3]);
      float it1 = sigm(gs1[0]), ft1 = sigm(gs1[1]), ch1 = tanhx(gs1[2]), ot1 = sigm(gs1[3]);
      float c0 = c_lds[bl][jj]   * ft0 + it0*ch0;
      float c1 = c_lds[bl][jj+1] * ft1 + it1*ch1;
      c_lds[bl][jj]   = c0;
      c_lds[bl][jj+1] = c1;
      float hv0 = ot0 * tanhx(c0);
      float hv1 = ot1 * tanhx(c1);
      u32 hp = (u32)(unsigned short)bf16b(hv0) | ((u32)(unsigned short)bf16b(hv1) << 16);
      __hip_atomic_store((u32*)(hout + (size_t)(b0 + bl)*HID + j0 + jj), hp,
                         __ATOMIC_RELAXED, __HIP_MEMORY_SCOPE_AGENT);
    }
    __syncthreads();   // part[] reusable; all waves' h stores drained (vmcnt0)

    if (t < SQLEN-1){
      if (tid == 0)
        __hip_atomic_store(myflags + jg, (u32)(t+1),
                           __ATOMIC_RELAXED, __HIP_MEMORY_SCOPE_AGENT);
      if (wave == 0){
        const u32 target = (u32)(t+1);
        while (!__all((int)(__hip_atomic_load(myflags + lane, __ATOMIC_RELAXED,
                                              __HIP_MEMORY_SCOPE_AGENT) >= target)))
          __builtin_amdgcn_s_sleep(1);
      }
      __syncthreads();
    }
  }
}

// ---- phase 3: out[b][c] = h[b]. Wfc[c] + bfc[c], fp32 ----
__global__ __launch_bounds__(256) void fc_kernel(const short* __restrict__ h,
    const float* __restrict__ wfc, const float* __restrict__ bfc, float* __restrict__ out)
{
  __shared__ float hs[4][1024];
  int tid = threadIdx.x;
  int b0 = blockIdx.x*4;
  for (int i = tid; i < 4096; i += 256){
    int bb = i >> 10, k = i & 1023;
    hs[bb][k] = bf2f(h[(size_t)(b0+bb)*HID + k]);
  }
  __syncthreads();
  for (int c = tid; c < NCLS; c += 256){
    const float* w = wfc + (size_t)c*HID;
    float a0=0.f,a1=0.f,a2=0.f,a3=0.f;
    for (int k=0; k<1024; k+=4){
      float4 wv = *(const float4*)(w + k);
      a0 += wv.x*hs[0][k] + wv.y*hs[0][k+1] + wv.z*hs[0][k+2] + wv.w*hs[0][k+3];
      a1 += wv.x*hs[1][k] + wv.y*hs[1][k+1] + wv.z*hs[1][k+2] + wv.w*hs[1][k+3];
      a2 += wv.x*hs[2][k] + wv.y*hs[2][k+1] + wv.z*hs[2][k+2] + wv.w*hs[2][k+3];
      a3 += wv.x*hs[3][k] + wv.y*hs[3][k+1] + wv.z*hs[3][k+2] + wv.w*hs[3][k+3];
    }
    float bb = bfc[c];
    out[(size_t)(b0+0)*NCLS + c] = a0 + bb;
    out[(size_t)(b0+1)*NCLS + c] = a1 + bb;
    out[(size_t)(b0+2)*NCLS + c] = a2 + bb;
    out[(size_t)(b0+3)*NCLS + c] = a3 + bb;
  }
}

extern "C" void kernel_launch(void* const* d_in, const int* in_sizes, int n_in,
                              void* d_out, int out_size, void* d_ws, size_t ws_size,
                              hipStream_t stream) {
  const float* x   = (const float*)d_in[0];
  const float* Wxh = (const float*)d_in[1];
  const float* bxh = (const float*)d_in[2];
  const float* Whh = (const float*)d_in[3];
  const float* bhh = (const float*)d_in[4];
  const float* Wfc = (const float*)d_in[5];
  const float* bfc = (const float*)d_in[6];
  float* out = (float*)d_out;

  char* ws = (char*)d_ws;
  short*    xbf   = (short*)(ws + 0);            // 64MB
  short*    wxhb  = (short*)(ws + 67108864);     // 8MB
  short*    whhb  = (short*)(ws + 75497472);     // 8MB
  float*    biasg = (float*)(ws + 83886080);     // 16KB
  short*    xw    = (short*)(ws + 83951616);     // 256MB
  short*    h0    = (short*)(ws + 352387072);    // 256KB
  short*    h1    = (short*)(ws + 352649216);    // 256KB
  u32*      flags = (u32*)(ws + 352911360);      // 4 groups x 64 words

  hipMemsetAsync(ws + 352387072, 0, 2*262144 + 4096, stream);

  cast_x_kernel<<<32768, 256, 0, stream>>>(x, xbf);
  cast_w_kernel<<<4096, 256, 0, stream>>>(Wxh, wxhb);
  cast_w_kernel<<<4096, 256, 0, stream>>>(Whh, whhb);
  bias_kernel  <<<16,   256, 0, stream>>>(bxh, bhh, biasg);
  gemm_xw_kernel<<<8192, 256, 0, stream>>>(xbf, wxhb, biasg, xw);
  lstm_kernel  <<<256,  256, 0, stream>>>(whhb, xw, h0, h1, flags);
  fc_kernel    <<<32,   256, 0, stream>>>(h0, Wfc, bfc, out);
}

// Round 3
// 2948.635 us; speedup vs baseline: 2.4198x; 1.0667x over previous
//
#include <hip/hip_runtime.h>
#include <hip/hip_bf16.h>

typedef __attribute__((ext_vector_type(8))) short short8;
typedef __attribute__((ext_vector_type(4))) float f32x4;
typedef unsigned long long u64;
typedef unsigned int u32;

#define SQLEN 256
#define BATCH 128
#define HID   1024
#define G4    4096
#define NCLS  1000

static __device__ __forceinline__ float sigm(float x){ return 1.0f/(1.0f+__expf(-x)); }
static __device__ __forceinline__ float tanhx(float x){ return 2.0f/(1.0f+__expf(-2.0f*x)) - 1.0f; }
static __device__ __forceinline__ short bf16b(float x){
  __hip_bfloat16 h = __float2bfloat16(x);
  return __builtin_bit_cast(short, h);
}
static __device__ __forceinline__ float bf2f(short s){
  return __bfloat162float(__builtin_bit_cast(__hip_bfloat16, s));
}

// ---- prep: cast x [B][S][I] fp32 -> xbf [(s*128+b)][I] bf16 (permuted) ----
__global__ void cast_x_kernel(const float* __restrict__ x, short* __restrict__ xbf){
  int r = blockIdx.x;            // r = s*128 + b
  int s = r >> 7, b = r & 127;
  const float* src = x + ((size_t)b*SQLEN + s)*HID;
  short* dst = xbf + (size_t)r*HID;
  int k = threadIdx.x*4;
  float4 v = *(const float4*)(src + k);
  short4 o; o.x=bf16b(v.x); o.y=bf16b(v.y); o.z=bf16b(v.z); o.w=bf16b(v.w);
  *(short4*)(dst + k) = o;
}

__global__ void cast_w_kernel(const float* __restrict__ src, short* __restrict__ dst){
  int i = (blockIdx.x*256 + threadIdx.x)*4;
  float4 v = *(const float4*)(src + i);
  short4 o; o.x=bf16b(v.x); o.y=bf16b(v.y); o.z=bf16b(v.z); o.w=bf16b(v.w);
  *(short4*)(dst + i) = o;
}

__global__ void bias_kernel(const float* __restrict__ a, const float* __restrict__ b,
                            float* __restrict__ o){
  int i = blockIdx.x*256 + threadIdx.x;
  o[i] = a[i] + b[i];
}

// ---- phase 1: xw GEMM. Output in gate-blocked layout:
//   xw2[((s*64 + jg)*128 + b)*64 + g*16 + jj]   (s=seq, jg=hid/16, g=gate)
// so each lstm block reads one contiguous 4KB chunk per step.
__global__ __launch_bounds__(256,2) void gemm_xw_kernel(
    const short* __restrict__ A, const short* __restrict__ B,
    const float* __restrict__ bias, short* __restrict__ C)
{
  __shared__ __align__(16) short As[4096];   // [128][32]
  __shared__ __align__(16) short Bs[4096];
  const int tid = threadIdx.x;
  const int bm = blockIdx.x >> 5;     // 0..255  (= s index)
  const int bn = blockIdx.x & 31;     // 0..31
  const size_t r0 = (size_t)bm*128, n0 = (size_t)bn*128;
  const int lane = tid & 63, wave = tid >> 6;
  const int wm = (wave>>1)*64, wn = (wave&1)*64;
  const int l15 = lane & 15, quad = lane >> 4;

  f32x4 acc[4][4];
  #pragma unroll
  for (int m=0;m<4;++m)
    #pragma unroll
    for (int n=0;n<4;++n) acc[m][n] = (f32x4)0.0f;

  for (int kk = 0; kk < 32; ++kk){
    const int k0 = kk*32;
    short8 av[2], bv[2];
    #pragma unroll
    for (int rep=0; rep<2; ++rep){
      int c = rep*256 + tid;
      int row = c >> 2, ko = (c & 3)*8;
      av[rep] = *(const short8*)(A + (r0+row)*HID + k0 + ko);
      bv[rep] = *(const short8*)(B + (n0+row)*HID + k0 + ko);
    }
    __syncthreads();
    #pragma unroll
    for (int rep=0; rep<2; ++rep){
      int c = rep*256 + tid;
      *(short8*)(As + c*8) = av[rep];
      *(short8*)(Bs + c*8) = bv[rep];
    }
    __syncthreads();
    short8 af[4], bf[4];
    #pragma unroll
    for (int m=0;m<4;++m) af[m] = *(const short8*)(As + (wm + m*16 + l15)*32 + quad*8);
    #pragma unroll
    for (int n=0;n<4;++n) bf[n] = *(const short8*)(Bs + (wn + n*16 + l15)*32 + quad*8);
    #pragma unroll
    for (int m=0;m<4;++m)
      #pragma unroll
      for (int n=0;n<4;++n)
        acc[m][n] = __builtin_amdgcn_mfma_f32_16x16x32_bf16(af[m], bf[n], acc[m][n], 0,0,0);
  }
  __syncthreads();
  #pragma unroll
  for (int n=0;n<4;++n){
    int nn = (int)n0 + wn + n*16 + l15;           // 0..4095
    float bs = bias[nn];
    int g = nn >> 10, jcol = nn & 1023;
    int jgi = jcol >> 4, jji = jcol & 15;
    #pragma unroll
    for (int m=0;m<4;++m){
      #pragma unroll
      for (int rg=0; rg<4; ++rg){
        int rowin = wm + m*16 + quad*4 + rg;      // 0..127 (= batch b)
        size_t dst = (((size_t)bm*64 + jgi)*128 + rowin)*64 + g*16 + jji;
        C[dst] = bf16b(acc[m][n][rg] + bs);
      }
    }
  }
}

// ---- phase 2: persistent LSTM recurrence ----
// 256 blocks x 512 threads (8 waves). 4 b-groups (32 rows) x 64 j-groups (16 hid).
// K=1024 split 8 ways across waves -> Bf = 16 short8 = 64 VGPR/wave, truly
// register-resident. Cell state c lives in a thread register. Cross-wave gate
// reduction staged in 32KB LDS (gate-pairs). h via relaxed agent (sc1) atomics;
// per-block flag words polled lane-parallel by wave 0.
__global__ __launch_bounds__(512,2) void lstm_kernel(
    const short* __restrict__ whh, const short* __restrict__ xw,
    short* __restrict__ h0, short* __restrict__ h1, u32* __restrict__ flags)
{
  const int tid  = threadIdx.x;
  const int lane = tid & 63;
  const int wave = tid >> 6;         // K-slice 0..7 (128 each)
  const int l15  = lane & 15;
  const int quad = lane >> 4;
  const int bg = blockIdx.x >> 6;    // 0..3
  const int jg = blockIdx.x & 63;    // 0..63
  const int b0 = bg*32;
  const int j0 = jg*16;
  const int ks0 = wave*128;

  // Whh fragments -> registers (once). 16 frags = 64 VGPR.
  // B-frag: n = l15 (-> j0+l15), k = ks0 + kit*32 + quad*8 + j
  short8 Bf[4][4];
  #pragma unroll
  for (int g=0; g<4; ++g){
    const short* src = whh + (size_t)(g*1024 + j0 + l15)*HID + ks0 + quad*8;
    #pragma unroll
    for (int kit=0; kit<4; ++kit)
      Bf[g][kit] = *(const short8*)(src + kit*32);
  }

  __shared__ f32x4 part[8][4][64];   // 32 KB staging (gate-pair x mt)

  u32* myflags = flags + bg*64;

  // elementwise mapping: cell = tid (512 cells: bl 0..31 x jj 0..15)
  const int bl = tid >> 4;
  const int jj = tid & 15;
  const int mt_e = bl >> 4, re = bl & 15;
  const int ln = (re>>2)*16 + jj, rg = re & 3;
  float cc = 0.0f;                   // cell state in register

  for (int t = 0; t < SQLEN; ++t){
    const short* hin  = (t & 1) ? h1 : h0;
    short*       hout = (t & 1) ? h0 : h1;

    // prefetch xw (gate-blocked layout: contiguous 4KB per block per step)
    const short* xb = xw + (((size_t)t*64 + jg)*128 + b0 + bl)*64 + jj;
    short xwr[4];
    #pragma unroll
    for (int g=0; g<4; ++g) xwr[g] = xb[g*16];

    // A (h) fragments, this wave's K-slice: relaxed agent (sc1) loads
    short8 Af[2][4];
    #pragma unroll
    for (int kit=0; kit<4; ++kit){
      #pragma unroll
      for (int mt=0; mt<2; ++mt){
        const u64* p = (const u64*)(hin + (size_t)(b0 + mt*16 + l15)*HID + ks0 + kit*32 + quad*8);
        u64 v0 = __hip_atomic_load(p,   __ATOMIC_RELAXED, __HIP_MEMORY_SCOPE_AGENT);
        u64 v1 = __hip_atomic_load(p+1, __ATOMIC_RELAXED, __HIP_MEMORY_SCOPE_AGENT);
        u64 vv[2] = {v0, v1};
        Af[mt][kit] = __builtin_bit_cast(short8, *(const __attribute__((ext_vector_type(2))) u64*)vv);
      }
    }

    f32x4 acc[2][4];
    #pragma unroll
    for (int mt=0; mt<2; ++mt)
      #pragma unroll
      for (int g=0; g<4; ++g) acc[mt][g] = (f32x4)0.0f;
    #pragma unroll
    for (int kit=0; kit<4; ++kit){
      #pragma unroll
      for (int g=0; g<4; ++g){
        acc[0][g] = __builtin_amdgcn_mfma_f32_16x16x32_bf16(Af[0][kit], Bf[g][kit], acc[0][g],0,0,0);
        acc[1][g] = __builtin_amdgcn_mfma_f32_16x16x32_bf16(Af[1][kit], Bf[g][kit], acc[1][g],0,0,0);
      }
    }

    // ---- stage 1: gates i (0), f (1); part[w][mt*2+gi][lane]
    part[wave][0][lane] = acc[0][0];
    part[wave][1][lane] = acc[0][1];
    part[wave][2][lane] = acc[1][0];
    part[wave][3][lane] = acc[1][1];
    __syncthreads();
    float gi = bf2f(xwr[0]), gf = bf2f(xwr[1]);
    #pragma unroll
    for (int w=0; w<8; ++w){
      const float* pi = (const float*)&part[w][mt_e*2+0][ln];
      const float* pf = (const float*)&part[w][mt_e*2+1][ln];
      gi += pi[rg]; gf += pf[rg];
    }
    float it = sigm(gi), ft = sigm(gf);
    float ctmp = cc * ft;
    __syncthreads();   // stage-1 reads done; part reusable

    // ---- stage 2: gates chat (2), o (3)
    part[wave][0][lane] = acc[0][2];
    part[wave][1][lane] = acc[0][3];
    part[wave][2][lane] = acc[1][2];
    part[wave][3][lane] = acc[1][3];
    __syncthreads();
    float gc = bf2f(xwr[2]), go = bf2f(xwr[3]);
    #pragma unroll
    for (int w=0; w<8; ++w){
      const float* pc = (const float*)&part[w][mt_e*2+0][ln];
      const float* po = (const float*)&part[w][mt_e*2+1][ln];
      gc += pc[rg]; go += po[rg];
    }
    float ch = tanhx(gc), ot = sigm(go);
    cc = ctmp + it*ch;
    float hv = ot * tanhx(cc);

    // pack adjacent-jj pair, even lanes store u32 (sc1)
    float hv1 = __shfl_down(hv, 1);
    if (!(lane & 1)){
      u32 hp = (u32)(unsigned short)bf16b(hv) | ((u32)(unsigned short)bf16b(hv1) << 16);
      __hip_atomic_store((u32*)(hout + (size_t)(b0 + bl)*HID + j0 + jj), hp,
                         __ATOMIC_RELAXED, __HIP_MEMORY_SCOPE_AGENT);
    }
    __syncthreads();   // h stores drained (vmcnt0 at barrier)

    if (t < SQLEN-1){
      if (tid == 0)
        __hip_atomic_store(myflags + jg, (u32)(t+1),
                           __ATOMIC_RELAXED, __HIP_MEMORY_SCOPE_AGENT);
      if (wave == 0){
        const u32 target = (u32)(t+1);
        while (!__all((int)(__hip_atomic_load(myflags + lane, __ATOMIC_RELAXED,
                                              __HIP_MEMORY_SCOPE_AGENT) >= target)))
          __builtin_amdgcn_s_sleep(1);
      }
      __syncthreads();
    }
  }
}

// ---- phase 3: out[b][c] = h[b]. Wfc[c] + bfc[c], fp32 ----
__global__ __launch_bounds__(256) void fc_kernel(const short* __restrict__ h,
    const float* __restrict__ wfc, const float* __restrict__ bfc, float* __restrict__ out)
{
  __shared__ float hs[4][1024];
  int tid = threadIdx.x;
  int b0 = blockIdx.x*4;
  for (int i = tid; i < 4096; i += 256){
    int bb = i >> 10, k = i & 1023;
    hs[bb][k] = bf2f(h[(size_t)(b0+bb)*HID + k]);
  }
  __syncthreads();
  for (int c = tid; c < NCLS; c += 256){
    const float* w = wfc + (size_t)c*HID;
    float a0=0.f,a1=0.f,a2=0.f,a3=0.f;
    for (int k=0; k<1024; k+=4){
      float4 wv = *(const float4*)(w + k);
      a0 += wv.x*hs[0][k] + wv.y*hs[0][k+1] + wv.z*hs[0][k+2] + wv.w*hs[0][k+3];
      a1 += wv.x*hs[1][k] + wv.y*hs[1][k+1] + wv.z*hs[1][k+2] + wv.w*hs[1][k+3];
      a2 += wv.x*hs[2][k] + wv.y*hs[2][k+1] + wv.z*hs[2][k+2] + wv.w*hs[2][k+3];
      a3 += wv.x*hs[3][k] + wv.y*hs[3][k+1] + wv.z*hs[3][k+2] + wv.w*hs[3][k+3];
    }
    float bb = bfc[c];
    out[(size_t)(b0+0)*NCLS + c] = a0 + bb;
    out[(size_t)(b0+1)*NCLS + c] = a1 + bb;
    out[(size_t)(b0+2)*NCLS + c] = a2 + bb;
    out[(size_t)(b0+3)*NCLS + c] = a3 + bb;
  }
}

extern "C" void kernel_launch(void* const* d_in, const int* in_sizes, int n_in,
                              void* d_out, int out_size, void* d_ws, size_t ws_size,
                              hipStream_t stream) {
  const float* x   = (const float*)d_in[0];
  const float* Wxh = (const float*)d_in[1];
  const float* bxh = (const float*)d_in[2];
  const float* Whh = (const float*)d_in[3];
  const float* bhh = (const float*)d_in[4];
  const float* Wfc = (const float*)d_in[5];
  const float* bfc = (const float*)d_in[6];
  float* out = (float*)d_out;

  char* ws = (char*)d_ws;
  short*    xbf   = (short*)(ws + 0);            // 64MB
  short*    wxhb  = (short*)(ws + 67108864);     // 8MB
  short*    whhb  = (short*)(ws + 75497472);     // 8MB
  float*    biasg = (float*)(ws + 83886080);     // 16KB
  short*    xw    = (short*)(ws + 83951616);     // 256MB (gate-blocked layout)
  short*    h0    = (short*)(ws + 352387072);    // 256KB
  short*    h1    = (short*)(ws + 352649216);    // 256KB
  u32*      flags = (u32*)(ws + 352911360);      // 4 groups x 64 words

  hipMemsetAsync(ws + 352387072, 0, 2*262144 + 4096, stream);

  cast_x_kernel<<<32768, 256, 0, stream>>>(x, xbf);
  cast_w_kernel<<<4096, 256, 0, stream>>>(Wxh, wxhb);
  cast_w_kernel<<<4096, 256, 0, stream>>>(Whh, whhb);
  bias_kernel  <<<16,   256, 0, stream>>>(bxh, bhh, biasg);
  gemm_xw_kernel<<<8192, 256, 0, stream>>>(xbf, wxhb, biasg, xw);
  lstm_kernel  <<<256,  512, 0, stream>>>(whhb, xw, h0, h1, flags);
  fc_kernel    <<<32,   256, 0, stream>>>(h0, Wfc, bfc, out);
}